// Round 1
// baseline (2096.839 us; speedup 1.0000x reference)
//
#include <hip/hip_runtime.h>

#define D   64
#define F3  192
#define BN  4

// Monotone float->uint encoding: order-preserving, 0 == "below all reals".
__device__ __forceinline__ unsigned enc_f32(float f) {
    unsigned u = __float_as_uint(f);
    return (u & 0x80000000u) ? ~u : (u | 0x80000000u);
}
__device__ __forceinline__ float dec_f32(unsigned u) {
    return (u & 0x80000000u) ? __uint_as_float(u ^ 0x80000000u)
                             : __uint_as_float(~u);
}

// Phase 1: edge scatter. 16 threads per edge, 4 channels each (float4 gather).
__global__ __launch_bounds__(256) void eg_scatter(
    const float* __restrict__ x,
    const int*   __restrict__ srcv,
    const int*   __restrict__ dstv,
    float*       __restrict__ sum,
    unsigned*    __restrict__ mxe,
    unsigned*    __restrict__ cnt,
    int E)
{
    int t = blockIdx.x * 256 + threadIdx.x;
    int e = t >> 4;
    if (e >= E) return;
    int c0 = (t & 15) << 2;               // channel base: 0,4,...,60
    int s = srcv[e];
    int d = dstv[e];
    float4 v = *reinterpret_cast<const float4*>(x + (size_t)s * D + c0);
    size_t base = (size_t)d * D + c0;
    atomicAdd(sum + base + 0, v.x);
    atomicAdd(sum + base + 1, v.y);
    atomicAdd(sum + base + 2, v.z);
    atomicAdd(sum + base + 3, v.w);
    atomicMax(mxe + base + 0, enc_f32(v.x));
    atomicMax(mxe + base + 1, enc_f32(v.y));
    atomicMax(mxe + base + 2, enc_f32(v.z));
    atomicMax(mxe + base + 3, enc_f32(v.w));
    if ((t & 15) == 0) atomicAdd(cnt + d, 1u);
}

// Phase 2: feats = [sum | mean | max] (192) -> out = feats @ W^T + b (64).
// Block: 256 threads = BN nodes x 64 output channels. W in LDS, transposed
// [f][o] with stride 65 (conflict-free on both the staging write and the
// compute read: lanes read consecutive o).
__global__ __launch_bounds__(256) void eg_mlp(
    const float*    __restrict__ sum,
    const unsigned* __restrict__ mxe,
    const unsigned* __restrict__ cnt,
    const float*    __restrict__ W,     // [64][192] row-major
    const float*    __restrict__ bias,  // [64]
    float*          __restrict__ out,
    int N)
{
    __shared__ float Wl[F3 * 65];       // [f][o], padded stride 65
    __shared__ float fl[BN][F3 + 8];

    int tid = threadIdx.x;
    for (int i = tid; i < D * F3; i += 256) {
        int o = i / F3;
        int f = i - o * F3;
        Wl[f * 65 + o] = W[i];          // coalesced global read
    }

    int nl = tid >> 6;
    int o  = tid & 63;
    int n  = blockIdx.x * BN + nl;
    if (n < N) {
        float    s = sum[(size_t)n * D + o];
        unsigned c = cnt[n];
        float    m = dec_f32(mxe[(size_t)n * D + o]);
        fl[nl][o]         = s;
        fl[nl][D + o]     = s / (float)(c > 0u ? c : 1u);
        fl[nl][2 * D + o] = (c > 0u) ? m : 0.0f;
    }
    __syncthreads();
    if (n >= N) return;

    float acc = bias[o];
    #pragma unroll 16
    for (int f = 0; f < F3; ++f)
        acc = fmaf(fl[nl][f], Wl[f * 65 + o], acc);
    out[(size_t)n * D + o] = acc;
}

extern "C" void kernel_launch(void* const* d_in, const int* in_sizes, int n_in,
                              void* d_out, int out_size, void* d_ws, size_t ws_size,
                              hipStream_t stream)
{
    const float* x  = (const float*)d_in[0];
    const int*   ei = (const int*)d_in[1];
    const float* W  = (const float*)d_in[2];
    const float* b  = (const float*)d_in[3];
    float* out = (float*)d_out;

    int N = in_sizes[0] / D;
    int E = in_sizes[1] / 2;
    const int* srcv = ei;
    const int* dstv = ei + E;

    float*    sum = (float*)d_ws;
    unsigned* mxe = (unsigned*)((char*)d_ws + (size_t)N * D * sizeof(float));
    unsigned* cnt = (unsigned*)((char*)d_ws + (size_t)2 * N * D * sizeof(float));
    size_t need = (size_t)2 * N * D * sizeof(float) + (size_t)N * sizeof(unsigned);
    hipMemsetAsync(d_ws, 0, need, stream);

    long long threads1 = (long long)E * 16;
    int grid1 = (int)((threads1 + 255) / 256);
    eg_scatter<<<grid1, 256, 0, stream>>>(x, srcv, dstv, sum, mxe, cnt, E);

    int grid2 = (N + BN - 1) / BN;
    eg_mlp<<<grid2, 256, 0, stream>>>(sum, mxe, cnt, W, b, out, N);
}

// Round 2
// 1101.757 us; speedup vs baseline: 1.9032x; 1.9032x over previous
//
#include <hip/hip_runtime.h>
#include <math.h>

#define D    64
#define F3   192
#define SCAN_CHUNK 2048   // 256 threads * 8 elements

// ---------------- Phase A: CSR construction ----------------

// A1: histogram of dst
__global__ __launch_bounds__(256) void k_hist(
    const int* __restrict__ dstv, unsigned* __restrict__ cnt, int E)
{
    int e = blockIdx.x * 256 + threadIdx.x;
    if (e < E) atomicAdd(&cnt[dstv[e]], 1u);
}

// A2: per-chunk exclusive scan (chunk-local) + chunk totals
__global__ __launch_bounds__(256) void k_chunk_scan(
    const unsigned* __restrict__ cnt, unsigned* __restrict__ offs,
    unsigned* __restrict__ partials, int N)
{
    __shared__ unsigned ts[256];
    int t = threadIdx.x;
    int ebase = blockIdx.x * SCAN_CHUNK + t * 8;
    unsigned v[8];
    unsigned s = 0;
    #pragma unroll
    for (int j = 0; j < 8; ++j) {
        unsigned c = (ebase + j < N) ? cnt[ebase + j] : 0u;
        v[j] = s; s += c;
    }
    ts[t] = s;
    __syncthreads();
    #pragma unroll
    for (int off = 1; off < 256; off <<= 1) {
        unsigned add = (t >= off) ? ts[t - off] : 0u;
        __syncthreads();
        ts[t] += add;
        __syncthreads();
    }
    unsigned tb = (t > 0) ? ts[t - 1] : 0u;
    #pragma unroll
    for (int j = 0; j < 8; ++j)
        if (ebase + j < N) offs[ebase + j] = tb + v[j];
    if (t == 255) partials[blockIdx.x] = ts[255];
}

// A3: serial exclusive scan of chunk totals (<=64 entries)
__global__ void k_scan_partials(unsigned* partials, int n)
{
    if (blockIdx.x == 0 && threadIdx.x == 0) {
        unsigned s = 0;
        for (int i = 0; i < n; ++i) { unsigned c = partials[i]; partials[i] = s; s += c; }
    }
}

// A4: add chunk base; duplicate into cursor
__global__ __launch_bounds__(256) void k_add_base(
    unsigned* __restrict__ offs, unsigned* __restrict__ cursor,
    const unsigned* __restrict__ partials, int N)
{
    int i = blockIdx.x * 256 + threadIdx.x;
    if (i < N) {
        unsigned o = offs[i] + partials[i / SCAN_CHUNK];
        offs[i] = o;
        cursor[i] = o;
    }
}

// A5: bucket src by dst
__global__ __launch_bounds__(256) void k_reorder(
    const int* __restrict__ srcv, const int* __restrict__ dstv,
    unsigned* __restrict__ cursor, unsigned* __restrict__ ssrc, int E)
{
    int e = blockIdx.x * 256 + threadIdx.x;
    if (e >= E) return;
    unsigned p = atomicAdd(&cursor[dstv[e]], 1u);
    ssrc[p] = (unsigned)srcv[e];
}

// ---------------- Phase B: fused gather + MLP ----------------
// One wave per node (lane = channel). Gather sum/max in registers,
// then out[n][o] = b[o] + sum_f feats[f] * W[o][f] via shfl broadcast
// against LDS-staged W^T [f][o], stride 65 (conflict-free read & write).
__global__ __launch_bounds__(256) void k_gather_mlp(
    const float*    __restrict__ x,
    const unsigned* __restrict__ ssrc,
    const unsigned* __restrict__ offs,
    const unsigned* __restrict__ cnt,
    const float*    __restrict__ W,     // [64][192] row-major
    const float*    __restrict__ bias,  // [64]
    float*          __restrict__ out,
    int N)
{
    __shared__ float Wl[F3 * 65];
    int tid = threadIdx.x;
    for (int i = tid; i < D * F3; i += 256) {
        int o = i / F3, f = i - o * F3;
        Wl[f * 65 + o] = W[i];
    }
    __syncthreads();

    int lane = tid & 63;
    int wv   = tid >> 6;
    float bo = bias[lane];

    for (int n = blockIdx.x * 4 + wv; n < N; n += gridDim.x * 4) {
        unsigned st = offs[n];
        unsigned dg = cnt[n];
        float sv = 0.0f, mv = -INFINITY;
        unsigned i = 0;
        for (; i + 2 <= dg; i += 2) {              // 2-way unroll for MLP latency
            unsigned s0 = ssrc[st + i], s1 = ssrc[st + i + 1];
            float a = x[(size_t)s0 * D + lane];
            float b = x[(size_t)s1 * D + lane];
            sv += a; sv += b;
            mv = fmaxf(mv, fmaxf(a, b));
        }
        if (i < dg) {
            float a = x[(size_t)ssrc[st + i] * D + lane];
            sv += a; mv = fmaxf(mv, a);
        }
        float mean = dg ? sv / (float)dg : 0.0f;
        float mx   = dg ? mv : 0.0f;

        float acc = bo;
        #pragma unroll
        for (int f = 0; f < 64; ++f) {
            acc = fmaf(__shfl(sv,   f), Wl[f * 65 + lane],         acc);
            acc = fmaf(__shfl(mean, f), Wl[(64  + f) * 65 + lane], acc);
            acc = fmaf(__shfl(mx,   f), Wl[(128 + f) * 65 + lane], acc);
        }
        out[(size_t)n * D + lane] = acc;
    }
}

extern "C" void kernel_launch(void* const* d_in, const int* in_sizes, int n_in,
                              void* d_out, int out_size, void* d_ws, size_t ws_size,
                              hipStream_t stream)
{
    const float* x  = (const float*)d_in[0];
    const int*   ei = (const int*)d_in[1];
    const float* W  = (const float*)d_in[2];
    const float* b  = (const float*)d_in[3];
    float* out = (float*)d_out;

    int N = in_sizes[0] / D;
    int E = in_sizes[1] / 2;
    const int* srcv = ei;
    const int* dstv = ei + E;

    unsigned* cnt      = (unsigned*)d_ws;
    unsigned* offs     = cnt + N;
    unsigned* cursor   = offs + N;
    unsigned* partials = cursor + N;
    unsigned* ssrc     = partials + 64;

    int nChunks = (N + SCAN_CHUNK - 1) / SCAN_CHUNK;

    hipMemsetAsync(cnt, 0, (size_t)N * sizeof(unsigned), stream);

    int gE = (E + 255) / 256;
    int gN = (N + 255) / 256;
    k_hist<<<gE, 256, 0, stream>>>(dstv, cnt, E);
    k_chunk_scan<<<nChunks, 256, 0, stream>>>(cnt, offs, partials, N);
    k_scan_partials<<<1, 64, 0, stream>>>(partials, nChunks);
    k_add_base<<<gN, 256, 0, stream>>>(offs, cursor, partials, N);
    k_reorder<<<gE, 256, 0, stream>>>(srcv, dstv, cursor, ssrc, E);
    k_gather_mlp<<<2048, 256, 0, stream>>>(x, ssrc, offs, cnt, W, b, out, N);
}

// Round 3
// 323.642 us; speedup vs baseline: 6.4789x; 3.4043x over previous
//
#include <hip/hip_runtime.h>
#include <hip/hip_bf16.h>
#include <math.h>

#define D    64
#define F3   192
#define SCAN_CHUNK 2048   // 256 threads * 8 elements

// ---------------- Phase A: CSR construction ----------------

__global__ __launch_bounds__(256) void k_hist(
    const int* __restrict__ dstv, unsigned* __restrict__ cnt, int E)
{
    int e = blockIdx.x * 256 + threadIdx.x;
    if (e < E) atomicAdd(&cnt[dstv[e]], 1u);
}

__global__ __launch_bounds__(256) void k_chunk_scan(
    const unsigned* __restrict__ cnt, unsigned* __restrict__ offs,
    unsigned* __restrict__ partials, int N)
{
    __shared__ unsigned ts[256];
    int t = threadIdx.x;
    int ebase = blockIdx.x * SCAN_CHUNK + t * 8;
    unsigned v[8];
    unsigned s = 0;
    #pragma unroll
    for (int j = 0; j < 8; ++j) {
        unsigned c = (ebase + j < N) ? cnt[ebase + j] : 0u;
        v[j] = s; s += c;
    }
    ts[t] = s;
    __syncthreads();
    #pragma unroll
    for (int off = 1; off < 256; off <<= 1) {
        unsigned add = (t >= off) ? ts[t - off] : 0u;
        __syncthreads();
        ts[t] += add;
        __syncthreads();
    }
    unsigned tb = (t > 0) ? ts[t - 1] : 0u;
    #pragma unroll
    for (int j = 0; j < 8; ++j)
        if (ebase + j < N) offs[ebase + j] = tb + v[j];
    if (t == 255) partials[blockIdx.x] = ts[255];
}

__global__ void k_scan_partials(unsigned* partials, int n)
{
    if (blockIdx.x == 0 && threadIdx.x == 0) {
        unsigned s = 0;
        for (int i = 0; i < n; ++i) { unsigned c = partials[i]; partials[i] = s; s += c; }
    }
}

__global__ __launch_bounds__(256) void k_add_base(
    unsigned* __restrict__ offs, unsigned* __restrict__ cursor,
    const unsigned* __restrict__ partials, int N)
{
    int i = blockIdx.x * 256 + threadIdx.x;
    if (i < N) {
        unsigned o = offs[i] + partials[i / SCAN_CHUNK];
        offs[i] = o;
        cursor[i] = o;
    }
}

__global__ __launch_bounds__(256) void k_reorder(
    const int* __restrict__ srcv, const int* __restrict__ dstv,
    unsigned* __restrict__ cursor, unsigned* __restrict__ ssrc, int E)
{
    int e = blockIdx.x * 256 + threadIdx.x;
    if (e >= E) return;
    unsigned p = atomicAdd(&cursor[dstv[e]], 1u);
    ssrc[p] = (unsigned)srcv[e];
}

// ---------------- Phase B: gather (wave = node, 4 edges in flight) ----------
// 64 lanes = 4 groups x 16 lanes; group g handles edges g, g+4, ...; each
// lane reads a float4 (4 channels) of the source row. Cross-group combine
// via 2 shfl_xor steps. Writes [sum|mean|max] as bf16 into feats.

__device__ __forceinline__ ushort f2bf(float f) {
    __hip_bfloat16 h = __float2bfloat16(f);
    return *reinterpret_cast<ushort*>(&h);
}

__global__ __launch_bounds__(256) void k_gather(
    const float*    __restrict__ x,
    const unsigned* __restrict__ ssrc,
    const unsigned* __restrict__ offs,
    const unsigned* __restrict__ cnt,
    ushort*         __restrict__ feats,   // [N][192] bf16
    int N)
{
    int tid  = threadIdx.x;
    int lane = tid & 63;
    int wv   = tid >> 6;
    int g    = lane >> 4;          // edge group 0..3
    int c4   = (lane & 15) << 2;   // channel base 0,4,...,60

    int n = blockIdx.x * 4 + wv;
    if (n >= N) return;

    unsigned st = offs[n];
    unsigned dg = cnt[n];

    float4 sv = make_float4(0.f, 0.f, 0.f, 0.f);
    float4 mv = make_float4(-INFINITY, -INFINITY, -INFINITY, -INFINITY);

    for (unsigned i = (unsigned)g; i < dg; i += 4) {
        unsigned s = ssrc[st + i];
        float4 v = *reinterpret_cast<const float4*>(x + (size_t)s * D + c4);
        sv.x += v.x; sv.y += v.y; sv.z += v.z; sv.w += v.w;
        mv.x = fmaxf(mv.x, v.x); mv.y = fmaxf(mv.y, v.y);
        mv.z = fmaxf(mv.z, v.z); mv.w = fmaxf(mv.w, v.w);
    }

    #pragma unroll
    for (int off = 16; off <= 32; off <<= 1) {
        sv.x += __shfl_xor(sv.x, off); sv.y += __shfl_xor(sv.y, off);
        sv.z += __shfl_xor(sv.z, off); sv.w += __shfl_xor(sv.w, off);
        mv.x = fmaxf(mv.x, __shfl_xor(mv.x, off));
        mv.y = fmaxf(mv.y, __shfl_xor(mv.y, off));
        mv.z = fmaxf(mv.z, __shfl_xor(mv.z, off));
        mv.w = fmaxf(mv.w, __shfl_xor(mv.w, off));
    }

    float inv = dg ? 1.0f / (float)dg : 0.0f;
    size_t rb = (size_t)n * F3;
    if (g == 0) {
        ushort4 u = { f2bf(sv.x), f2bf(sv.y), f2bf(sv.z), f2bf(sv.w) };
        *reinterpret_cast<ushort4*>(feats + rb + c4) = u;
    } else if (g == 1) {
        ushort4 u = { f2bf(sv.x * inv), f2bf(sv.y * inv),
                      f2bf(sv.z * inv), f2bf(sv.w * inv) };
        *reinterpret_cast<ushort4*>(feats + rb + D + c4) = u;
    } else if (g == 2) {
        float4 m = mv;
        if (dg == 0) m = make_float4(0.f, 0.f, 0.f, 0.f);
        ushort4 u = { f2bf(m.x), f2bf(m.y), f2bf(m.z), f2bf(m.w) };
        *reinterpret_cast<ushort4*>(feats + rb + 2 * D + c4) = u;
    }
}

// ---------------- Phase C: MLP ----------------
// Block = 256 threads = 4 waves; block covers 16 nodes (N divisible by 16).
// Wave w handles nodes 4w..4w+3; thread = (nodes, o=lane). Wl [f][o] stride
// 65 (conflict-free); fl broadcasts are same-address (free). Each Wl read
// amortized over 4 nodes; 4 independent acc chains.
__global__ __launch_bounds__(256) void k_mlp(
    const ushort* __restrict__ feats,   // [N][192] bf16
    const float*  __restrict__ W,       // [64][192]
    const float*  __restrict__ bias,    // [64]
    float*        __restrict__ out,
    int N)
{
    __shared__ float Wl[F3 * 65];
    __shared__ float fl[16][F3];

    int tid = threadIdx.x;
    for (int i = tid; i < D * F3; i += 256) {
        int o = i / F3, f = i - o * F3;
        Wl[f * 65 + o] = W[i];
    }
    {
        const ushort4* fb = reinterpret_cast<const ushort4*>(
            feats + (size_t)blockIdx.x * 16 * F3);
        float4* fd = reinterpret_cast<float4*>(&fl[0][0]);
        for (int i = tid; i < 16 * F3 / 4; i += 256) {
            ushort4 u = fb[i];
            float4 f;
            f.x = __bfloat162float(*reinterpret_cast<__hip_bfloat16*>(&u.x));
            f.y = __bfloat162float(*reinterpret_cast<__hip_bfloat16*>(&u.y));
            f.z = __bfloat162float(*reinterpret_cast<__hip_bfloat16*>(&u.z));
            f.w = __bfloat162float(*reinterpret_cast<__hip_bfloat16*>(&u.w));
            fd[i] = f;
        }
    }
    __syncthreads();

    int o  = tid & 63;
    int r0 = (tid >> 6) * 4;
    float bo = bias[o];
    float acc0 = bo, acc1 = bo, acc2 = bo, acc3 = bo;

    #pragma unroll 4
    for (int f = 0; f < F3; f += 4) {
        float w0 = Wl[(f + 0) * 65 + o];
        float w1 = Wl[(f + 1) * 65 + o];
        float w2 = Wl[(f + 2) * 65 + o];
        float w3 = Wl[(f + 3) * 65 + o];
        float4 a = *reinterpret_cast<const float4*>(&fl[r0 + 0][f]);
        float4 b = *reinterpret_cast<const float4*>(&fl[r0 + 1][f]);
        float4 c = *reinterpret_cast<const float4*>(&fl[r0 + 2][f]);
        float4 d = *reinterpret_cast<const float4*>(&fl[r0 + 3][f]);
        acc0 = fmaf(a.x, w0, acc0); acc0 = fmaf(a.y, w1, acc0);
        acc0 = fmaf(a.z, w2, acc0); acc0 = fmaf(a.w, w3, acc0);
        acc1 = fmaf(b.x, w0, acc1); acc1 = fmaf(b.y, w1, acc1);
        acc1 = fmaf(b.z, w2, acc1); acc1 = fmaf(b.w, w3, acc1);
        acc2 = fmaf(c.x, w0, acc2); acc2 = fmaf(c.y, w1, acc2);
        acc2 = fmaf(c.z, w2, acc2); acc2 = fmaf(c.w, w3, acc2);
        acc3 = fmaf(d.x, w0, acc3); acc3 = fmaf(d.y, w1, acc3);
        acc3 = fmaf(d.z, w2, acc3); acc3 = fmaf(d.w, w3, acc3);
    }

    size_t base = (size_t)blockIdx.x * 16 + r0;
    out[(base + 0) * D + o] = acc0;
    out[(base + 1) * D + o] = acc1;
    out[(base + 2) * D + o] = acc2;
    out[(base + 3) * D + o] = acc3;
}

extern "C" void kernel_launch(void* const* d_in, const int* in_sizes, int n_in,
                              void* d_out, int out_size, void* d_ws, size_t ws_size,
                              hipStream_t stream)
{
    const float* x  = (const float*)d_in[0];
    const int*   ei = (const int*)d_in[1];
    const float* W  = (const float*)d_in[2];
    const float* b  = (const float*)d_in[3];
    float* out = (float*)d_out;

    int N = in_sizes[0] / D;
    int E = in_sizes[1] / 2;
    const int* srcv = ei;
    const int* dstv = ei + E;

    unsigned* cnt      = (unsigned*)d_ws;
    unsigned* offs     = cnt + N;
    unsigned* cursor   = offs + N;
    unsigned* partials = cursor + N;
    unsigned* ssrc     = partials + 64;
    ushort*   feats    = (ushort*)(ssrc + E);   // [N][192] bf16, ~38.4 MB

    int nChunks = (N + SCAN_CHUNK - 1) / SCAN_CHUNK;

    hipMemsetAsync(cnt, 0, (size_t)N * sizeof(unsigned), stream);

    int gE = (E + 255) / 256;
    int gN = (N + 255) / 256;
    k_hist<<<gE, 256, 0, stream>>>(dstv, cnt, E);
    k_chunk_scan<<<nChunks, 256, 0, stream>>>(cnt, offs, partials, N);
    k_scan_partials<<<1, 64, 0, stream>>>(partials, nChunks);
    k_add_base<<<gN, 256, 0, stream>>>(offs, cursor, partials, N);
    k_reorder<<<gE, 256, 0, stream>>>(srcv, dstv, cursor, ssrc, E);

    k_gather<<<(N + 3) / 4, 256, 0, stream>>>(x, ssrc, offs, cnt, feats, N);
    k_mlp<<<N / 16, 256, 0, stream>>>(feats, W, b, out, N);
}

// Round 4
// 260.972 us; speedup vs baseline: 8.0347x; 1.2401x over previous
//
#include <hip/hip_runtime.h>
#include <hip/hip_bf16.h>
#include <math.h>

#define D    64
#define F3   192
#define SCAN_CHUNK 2048   // 256 threads * 8 elements

using bf16x8 = __attribute__((ext_vector_type(8))) short;
using f32x4  = __attribute__((ext_vector_type(4))) float;

// ---------------- Phase A: CSR construction ----------------

__global__ __launch_bounds__(256) void k_hist(
    const int* __restrict__ dstv, unsigned* __restrict__ cnt, int E)
{
    int e = blockIdx.x * 256 + threadIdx.x;
    if (e < E) atomicAdd(&cnt[dstv[e]], 1u);
}

__global__ __launch_bounds__(256) void k_chunk_scan(
    const unsigned* __restrict__ cnt, unsigned* __restrict__ offs,
    unsigned* __restrict__ partials, int N)
{
    __shared__ unsigned ts[256];
    int t = threadIdx.x;
    int ebase = blockIdx.x * SCAN_CHUNK + t * 8;
    unsigned v[8];
    unsigned s = 0;
    #pragma unroll
    for (int j = 0; j < 8; ++j) {
        unsigned c = (ebase + j < N) ? cnt[ebase + j] : 0u;
        v[j] = s; s += c;
    }
    ts[t] = s;
    __syncthreads();
    #pragma unroll
    for (int off = 1; off < 256; off <<= 1) {
        unsigned add = (t >= off) ? ts[t - off] : 0u;
        __syncthreads();
        ts[t] += add;
        __syncthreads();
    }
    unsigned tb = (t > 0) ? ts[t - 1] : 0u;
    #pragma unroll
    for (int j = 0; j < 8; ++j)
        if (ebase + j < N) offs[ebase + j] = tb + v[j];
    if (t == 255) partials[blockIdx.x] = ts[255];
}

__global__ void k_scan_partials(unsigned* partials, int n)
{
    if (blockIdx.x == 0 && threadIdx.x == 0) {
        unsigned s = 0;
        for (int i = 0; i < n; ++i) { unsigned c = partials[i]; partials[i] = s; s += c; }
    }
}

__global__ __launch_bounds__(256) void k_add_base(
    unsigned* __restrict__ offs, unsigned* __restrict__ cursor,
    const unsigned* __restrict__ partials, int N)
{
    int i = blockIdx.x * 256 + threadIdx.x;
    if (i < N) {
        unsigned o = offs[i] + partials[i / SCAN_CHUNK];
        offs[i] = o;
        cursor[i] = o;
    }
}

__global__ __launch_bounds__(256) void k_reorder(
    const int* __restrict__ srcv, const int* __restrict__ dstv,
    unsigned* __restrict__ cursor, unsigned* __restrict__ ssrc, int E)
{
    int e = blockIdx.x * 256 + threadIdx.x;
    if (e >= E) return;
    unsigned p = atomicAdd(&cursor[dstv[e]], 1u);
    ssrc[p] = (unsigned)srcv[e];
}

// ---------------- Phase B: gather (wave = node, 4 edges in flight) ----------

__device__ __forceinline__ ushort f2bf(float f) {
    __hip_bfloat16 h = __float2bfloat16(f);
    return *reinterpret_cast<ushort*>(&h);
}

__global__ __launch_bounds__(256) void k_gather(
    const float*    __restrict__ x,
    const unsigned* __restrict__ ssrc,
    const unsigned* __restrict__ offs,
    const unsigned* __restrict__ cnt,
    ushort*         __restrict__ feats,   // [N][192] bf16
    int N)
{
    int tid  = threadIdx.x;
    int lane = tid & 63;
    int wv   = tid >> 6;
    int g    = lane >> 4;          // edge group 0..3
    int c4   = (lane & 15) << 2;   // channel base 0,4,...,60

    int n = blockIdx.x * 4 + wv;
    if (n >= N) return;

    unsigned st = offs[n];
    unsigned dg = cnt[n];

    float4 sv = make_float4(0.f, 0.f, 0.f, 0.f);
    float4 mv = make_float4(-INFINITY, -INFINITY, -INFINITY, -INFINITY);

    for (unsigned i = (unsigned)g; i < dg; i += 4) {
        unsigned s = ssrc[st + i];
        float4 v = *reinterpret_cast<const float4*>(x + (size_t)s * D + c4);
        sv.x += v.x; sv.y += v.y; sv.z += v.z; sv.w += v.w;
        mv.x = fmaxf(mv.x, v.x); mv.y = fmaxf(mv.y, v.y);
        mv.z = fmaxf(mv.z, v.z); mv.w = fmaxf(mv.w, v.w);
    }

    #pragma unroll
    for (int off = 16; off <= 32; off <<= 1) {
        sv.x += __shfl_xor(sv.x, off); sv.y += __shfl_xor(sv.y, off);
        sv.z += __shfl_xor(sv.z, off); sv.w += __shfl_xor(sv.w, off);
        mv.x = fmaxf(mv.x, __shfl_xor(mv.x, off));
        mv.y = fmaxf(mv.y, __shfl_xor(mv.y, off));
        mv.z = fmaxf(mv.z, __shfl_xor(mv.z, off));
        mv.w = fmaxf(mv.w, __shfl_xor(mv.w, off));
    }

    float inv = dg ? 1.0f / (float)dg : 0.0f;
    size_t rb = (size_t)n * F3;
    if (g == 0) {
        ushort4 u = { f2bf(sv.x), f2bf(sv.y), f2bf(sv.z), f2bf(sv.w) };
        *reinterpret_cast<ushort4*>(feats + rb + c4) = u;
    } else if (g == 1) {
        ushort4 u = { f2bf(sv.x * inv), f2bf(sv.y * inv),
                      f2bf(sv.z * inv), f2bf(sv.w * inv) };
        *reinterpret_cast<ushort4*>(feats + rb + D + c4) = u;
    } else if (g == 2) {
        float4 m = mv;
        if (dg == 0) m = make_float4(0.f, 0.f, 0.f, 0.f);
        ushort4 u = { f2bf(m.x), f2bf(m.y), f2bf(m.z), f2bf(m.w) };
        *reinterpret_cast<ushort4*>(feats + rb + 2 * D + c4) = u;
    }
}

// ---------------- Phase C: MFMA MLP ----------------
// out[100000x64] = feats[100000x192](bf16) @ W^T(192x64, bf16-converted) + b.
// Wave = one 16-col block; B-frags (6 k-steps) hoisted into 24 VGPRs once;
// grid-stride over 16-node tiles. A-frag = one 16B bf16x8 load per k-step
// straight from feats (rows 384B-aligned). mfma_f32_16x16x32_bf16:
//   A: row=lane&15, k=(lane>>4)*8+j ; B: k=(lane>>4)*8+j, col=lane&15
//   C/D: col=lane&15, row=(lane>>4)*4+reg   [verified m89/m91]
__global__ __launch_bounds__(256) void k_mlp_mfma(
    const ushort* __restrict__ feats,   // [N][192] bf16
    const float*  __restrict__ W,       // [64][192] f32
    const float*  __restrict__ bias,    // [64]
    float*        __restrict__ out,     // [N][64]
    int N)
{
    int tid  = threadIdx.x;
    int lane = tid & 63;
    int c    = tid >> 6;                // col block 0..3 (wave in block)
    int l16  = lane & 15;
    int kb   = (lane >> 4) << 3;        // k sub-offset 0,8,16,24

    int col = (c << 4) + l16;
    const float* wrow = W + (size_t)col * F3;

    bf16x8 bfr[6];
    #pragma unroll
    for (int ks = 0; ks < 6; ++ks) {
        float4 lo = *reinterpret_cast<const float4*>(wrow + ks * 32 + kb);
        float4 hi = *reinterpret_cast<const float4*>(wrow + ks * 32 + kb + 4);
        bf16x8 bb;
        bb[0] = (short)f2bf(lo.x); bb[1] = (short)f2bf(lo.y);
        bb[2] = (short)f2bf(lo.z); bb[3] = (short)f2bf(lo.w);
        bb[4] = (short)f2bf(hi.x); bb[5] = (short)f2bf(hi.y);
        bb[6] = (short)f2bf(hi.z); bb[7] = (short)f2bf(hi.w);
        bfr[ks] = bb;
    }
    float bo = bias[col];

    int ntiles = N >> 4;                // N divisible by 16 (100000)
    for (int t = blockIdx.x; t < ntiles; t += gridDim.x) {
        int n0 = t << 4;
        const ushort* arow = feats + (size_t)(n0 + l16) * F3 + kb;
        bf16x8 afr[6];
        #pragma unroll
        for (int ks = 0; ks < 6; ++ks)
            afr[ks] = *reinterpret_cast<const bf16x8*>(arow + ks * 32);

        f32x4 acc = { bo, bo, bo, bo };
        #pragma unroll
        for (int ks = 0; ks < 6; ++ks)
            acc = __builtin_amdgcn_mfma_f32_16x16x32_bf16(afr[ks], bfr[ks], acc, 0, 0, 0);

        int rbase = n0 + ((lane >> 4) << 2);
        #pragma unroll
        for (int r = 0; r < 4; ++r)
            out[(size_t)(rbase + r) * D + col] = acc[r];
    }
}

extern "C" void kernel_launch(void* const* d_in, const int* in_sizes, int n_in,
                              void* d_out, int out_size, void* d_ws, size_t ws_size,
                              hipStream_t stream)
{
    const float* x  = (const float*)d_in[0];
    const int*   ei = (const int*)d_in[1];
    const float* W  = (const float*)d_in[2];
    const float* b  = (const float*)d_in[3];
    float* out = (float*)d_out;

    int N = in_sizes[0] / D;
    int E = in_sizes[1] / 2;
    const int* srcv = ei;
    const int* dstv = ei + E;

    unsigned* cnt      = (unsigned*)d_ws;
    unsigned* offs     = cnt + N;
    unsigned* cursor   = offs + N;
    unsigned* partials = cursor + N;
    unsigned* ssrc     = partials + 64;
    ushort*   feats    = (ushort*)(ssrc + E);   // [N][192] bf16, ~38.4 MB

    int nChunks = (N + SCAN_CHUNK - 1) / SCAN_CHUNK;

    hipMemsetAsync(cnt, 0, (size_t)N * sizeof(unsigned), stream);

    int gE = (E + 255) / 256;
    int gN = (N + 255) / 256;
    k_hist<<<gE, 256, 0, stream>>>(dstv, cnt, E);
    k_chunk_scan<<<nChunks, 256, 0, stream>>>(cnt, offs, partials, N);
    k_scan_partials<<<1, 64, 0, stream>>>(partials, nChunks);
    k_add_base<<<gN, 256, 0, stream>>>(offs, cursor, partials, N);
    k_reorder<<<gE, 256, 0, stream>>>(srcv, dstv, cursor, ssrc, E);

    k_gather<<<(N + 3) / 4, 256, 0, stream>>>(x, ssrc, offs, cnt, feats, N);
    k_mlp_mfma<<<1024, 256, 0, stream>>>(feats, W, b, out, N);
}

// Round 5
// 133.444 us; speedup vs baseline: 15.7132x; 1.9557x over previous
//
#include <hip/hip_runtime.h>
#include <hip/hip_bf16.h>
#include <math.h>

#define D    64
#define F3   192
#define NPB  256          // nodes per bucket (local dst = 8 bits)
#define LBITS 8
#define SBITS 17          // src id fits in 17 bits (N=100000 < 131072)
#define NBLK 256          // edge blocks for binning passes
#define SCAN_CHUNK 2048   // 256 threads * 8 elements

using bf16x8 = __attribute__((ext_vector_type(8))) short;
using f32x4  = __attribute__((ext_vector_type(4))) float;

// ---------------- Phase A: bucketed CSR construction ----------------

// A1: per-(edge-block, bucket) histogram, stored transposed [bucket][block].
__global__ __launch_bounds__(256) void k_bin_hist(
    const int* __restrict__ dstv, unsigned* __restrict__ bcntT,
    int E, int EPB, int NB)
{
    __shared__ unsigned h[512];
    for (int i = threadIdx.x; i < NB; i += 256) h[i] = 0;
    __syncthreads();
    int lo = blockIdx.x * EPB, hi = min(E, lo + EPB);
    for (int e = lo + threadIdx.x; e < hi; e += 256)
        atomicAdd(&h[((unsigned)dstv[e]) >> LBITS], 1u);
    __syncthreads();
    for (int i = threadIdx.x; i < NB; i += 256)
        bcntT[(size_t)i * NBLK + blockIdx.x] = h[i];
}

// A2: chunked exclusive scan (generic length)
__global__ __launch_bounds__(256) void k_chunk_scan(
    const unsigned* __restrict__ cnt, unsigned* __restrict__ offs,
    unsigned* __restrict__ partials, int N)
{
    __shared__ unsigned ts[256];
    int t = threadIdx.x;
    int ebase = blockIdx.x * SCAN_CHUNK + t * 8;
    unsigned v[8];
    unsigned s = 0;
    #pragma unroll
    for (int j = 0; j < 8; ++j) {
        unsigned c = (ebase + j < N) ? cnt[ebase + j] : 0u;
        v[j] = s; s += c;
    }
    ts[t] = s;
    __syncthreads();
    #pragma unroll
    for (int off = 1; off < 256; off <<= 1) {
        unsigned add = (t >= off) ? ts[t - off] : 0u;
        __syncthreads();
        ts[t] += add;
        __syncthreads();
    }
    unsigned tb = (t > 0) ? ts[t - 1] : 0u;
    #pragma unroll
    for (int j = 0; j < 8; ++j)
        if (ebase + j < N) offs[ebase + j] = tb + v[j];
    if (t == 255) partials[blockIdx.x] = ts[255];
}

__global__ void k_scan_partials(unsigned* partials, int n)
{
    if (blockIdx.x == 0 && threadIdx.x == 0) {
        unsigned s = 0;
        for (int i = 0; i < n; ++i) { unsigned c = partials[i]; partials[i] = s; s += c; }
    }
}

__global__ __launch_bounds__(256) void k_add_base(
    unsigned* __restrict__ offs, const unsigned* __restrict__ partials, int N)
{
    int i = blockIdx.x * 256 + threadIdx.x;
    if (i < N) offs[i] += partials[i / SCAN_CHUNK];
}

// A3: scatter edges into bucket-grouped storage. LDS cursors -> writes for a
// given (block,bucket) form a dense run; packed entry = localdst<<17 | src.
__global__ __launch_bounds__(256) void k_bin_scatter(
    const int* __restrict__ srcv, const int* __restrict__ dstv,
    const unsigned* __restrict__ bbaseT, unsigned* __restrict__ binned,
    int E, int EPB, int NB)
{
    __shared__ unsigned cur[512];
    for (int i = threadIdx.x; i < NB; i += 256)
        cur[i] = bbaseT[(size_t)i * NBLK + blockIdx.x];
    __syncthreads();
    int lo = blockIdx.x * EPB, hi = min(E, lo + EPB);
    for (int e = lo + threadIdx.x; e < hi; e += 256) {
        unsigned d = (unsigned)dstv[e];
        unsigned s = (unsigned)srcv[e];
        unsigned p = atomicAdd(&cur[d >> LBITS], 1u);
        binned[p] = ((d & (NPB - 1u)) << SBITS) | s;
    }
}

// A4: one block per bucket. Node hist + scan + scatter entirely in LDS;
// writes offs/cnt coalesced and ssrc into a dense ~12.5 KB region.
__global__ __launch_bounds__(256) void k_bucket_csr(
    const unsigned* __restrict__ binned, const unsigned* __restrict__ bbaseT,
    unsigned* __restrict__ offs, unsigned* __restrict__ cnt,
    unsigned* __restrict__ ssrc, int E, int NB, int N)
{
    __shared__ unsigned c[256];
    __shared__ unsigned ts[256];
    int k = blockIdx.x;
    int t = threadIdx.x;
    unsigned bstart = bbaseT[(size_t)k * NBLK];
    unsigned bend   = (k + 1 < NB) ? bbaseT[(size_t)(k + 1) * NBLK] : (unsigned)E;

    c[t] = 0;
    __syncthreads();
    for (unsigned e = bstart + t; e < bend; e += 256)
        atomicAdd(&c[binned[e] >> SBITS], 1u);
    __syncthreads();

    unsigned myc = c[t];
    ts[t] = myc;
    __syncthreads();
    #pragma unroll
    for (int off = 1; off < 256; off <<= 1) {
        unsigned add = (t >= off) ? ts[t - off] : 0u;
        __syncthreads();
        ts[t] += add;
        __syncthreads();
    }
    unsigned excl = t ? ts[t - 1] : 0u;

    int gn = k * NPB + t;
    if (gn < N) { offs[gn] = bstart + excl; cnt[gn] = myc; }

    c[t] = excl;          // becomes local cursor
    __syncthreads();
    for (unsigned e = bstart + t; e < bend; e += 256) {
        unsigned u  = binned[e];
        unsigned ld = u >> SBITS;
        unsigned r  = atomicAdd(&c[ld], 1u);
        ssrc[bstart + r] = u & ((1u << SBITS) - 1u);
    }
}

// ---------------- Phase B: gather (wave = node, 4 edges in flight) ----------

__device__ __forceinline__ ushort f2bf(float f) {
    __hip_bfloat16 h = __float2bfloat16(f);
    return *reinterpret_cast<ushort*>(&h);
}

__global__ __launch_bounds__(256) void k_gather(
    const float*    __restrict__ x,
    const unsigned* __restrict__ ssrc,
    const unsigned* __restrict__ offs,
    const unsigned* __restrict__ cnt,
    ushort*         __restrict__ feats,   // [N][192] bf16
    int N)
{
    int tid  = threadIdx.x;
    int lane = tid & 63;
    int wv   = tid >> 6;
    int g    = lane >> 4;          // edge group 0..3
    int c4   = (lane & 15) << 2;   // channel base 0,4,...,60

    int n = blockIdx.x * 4 + wv;
    if (n >= N) return;

    unsigned st = offs[n];
    unsigned dg = cnt[n];

    float4 sv = make_float4(0.f, 0.f, 0.f, 0.f);
    float4 mv = make_float4(-INFINITY, -INFINITY, -INFINITY, -INFINITY);

    for (unsigned i = (unsigned)g; i < dg; i += 4) {
        unsigned s = ssrc[st + i];
        float4 v = *reinterpret_cast<const float4*>(x + (size_t)s * D + c4);
        sv.x += v.x; sv.y += v.y; sv.z += v.z; sv.w += v.w;
        mv.x = fmaxf(mv.x, v.x); mv.y = fmaxf(mv.y, v.y);
        mv.z = fmaxf(mv.z, v.z); mv.w = fmaxf(mv.w, v.w);
    }

    #pragma unroll
    for (int off = 16; off <= 32; off <<= 1) {
        sv.x += __shfl_xor(sv.x, off); sv.y += __shfl_xor(sv.y, off);
        sv.z += __shfl_xor(sv.z, off); sv.w += __shfl_xor(sv.w, off);
        mv.x = fmaxf(mv.x, __shfl_xor(mv.x, off));
        mv.y = fmaxf(mv.y, __shfl_xor(mv.y, off));
        mv.z = fmaxf(mv.z, __shfl_xor(mv.z, off));
        mv.w = fmaxf(mv.w, __shfl_xor(mv.w, off));
    }

    float inv = dg ? 1.0f / (float)dg : 0.0f;
    size_t rb = (size_t)n * F3;
    if (g == 0) {
        ushort4 u = { f2bf(sv.x), f2bf(sv.y), f2bf(sv.z), f2bf(sv.w) };
        *reinterpret_cast<ushort4*>(feats + rb + c4) = u;
    } else if (g == 1) {
        ushort4 u = { f2bf(sv.x * inv), f2bf(sv.y * inv),
                      f2bf(sv.z * inv), f2bf(sv.w * inv) };
        *reinterpret_cast<ushort4*>(feats + rb + D + c4) = u;
    } else if (g == 2) {
        float4 m = mv;
        if (dg == 0) m = make_float4(0.f, 0.f, 0.f, 0.f);
        ushort4 u = { f2bf(m.x), f2bf(m.y), f2bf(m.z), f2bf(m.w) };
        *reinterpret_cast<ushort4*>(feats + rb + 2 * D + c4) = u;
    }
}

// ---------------- Phase C: MFMA MLP ----------------
__global__ __launch_bounds__(256) void k_mlp_mfma(
    const ushort* __restrict__ feats,   // [N][192] bf16
    const float*  __restrict__ W,       // [64][192] f32
    const float*  __restrict__ bias,    // [64]
    float*        __restrict__ out,     // [N][64]
    int N)
{
    int tid  = threadIdx.x;
    int lane = tid & 63;
    int c    = tid >> 6;
    int l16  = lane & 15;
    int kb   = (lane >> 4) << 3;

    int col = (c << 4) + l16;
    const float* wrow = W + (size_t)col * F3;

    bf16x8 bfr[6];
    #pragma unroll
    for (int ks = 0; ks < 6; ++ks) {
        float4 lo = *reinterpret_cast<const float4*>(wrow + ks * 32 + kb);
        float4 hi = *reinterpret_cast<const float4*>(wrow + ks * 32 + kb + 4);
        bf16x8 bb;
        bb[0] = (short)f2bf(lo.x); bb[1] = (short)f2bf(lo.y);
        bb[2] = (short)f2bf(lo.z); bb[3] = (short)f2bf(lo.w);
        bb[4] = (short)f2bf(hi.x); bb[5] = (short)f2bf(hi.y);
        bb[6] = (short)f2bf(hi.z); bb[7] = (short)f2bf(hi.w);
        bfr[ks] = bb;
    }
    float bo = bias[col];

    int ntiles = N >> 4;
    for (int t = blockIdx.x; t < ntiles; t += gridDim.x) {
        int n0 = t << 4;
        const ushort* arow = feats + (size_t)(n0 + l16) * F3 + kb;
        bf16x8 afr[6];
        #pragma unroll
        for (int ks = 0; ks < 6; ++ks)
            afr[ks] = *reinterpret_cast<const bf16x8*>(arow + ks * 32);

        f32x4 acc = { bo, bo, bo, bo };
        #pragma unroll
        for (int ks = 0; ks < 6; ++ks)
            acc = __builtin_amdgcn_mfma_f32_16x16x32_bf16(afr[ks], bfr[ks], acc, 0, 0, 0);

        int rbase = n0 + ((lane >> 4) << 2);
        #pragma unroll
        for (int r = 0; r < 4; ++r)
            out[(size_t)(rbase + r) * D + col] = acc[r];
    }
}

extern "C" void kernel_launch(void* const* d_in, const int* in_sizes, int n_in,
                              void* d_out, int out_size, void* d_ws, size_t ws_size,
                              hipStream_t stream)
{
    const float* x  = (const float*)d_in[0];
    const int*   ei = (const int*)d_in[1];
    const float* W  = (const float*)d_in[2];
    const float* b  = (const float*)d_in[3];
    float* out = (float*)d_out;

    int N = in_sizes[0] / D;
    int E = in_sizes[1] / 2;
    const int* srcv = ei;
    const int* dstv = ei + E;

    int NB  = (N + NPB - 1) / NPB;          // 391 buckets
    int EPB = (E + NBLK - 1) / NBLK;        // edges per bin-block
    int M   = NB * NBLK;                    // count-matrix size

    unsigned* bcntT    = (unsigned*)d_ws;   // [M]
    unsigned* bbaseT   = bcntT + M;         // [M]
    unsigned* partials = bbaseT + M;        // [64]
    unsigned* offs     = partials + 64;     // [N]
    unsigned* cnt      = offs + N;          // [N]
    unsigned* ssrc     = cnt + N;           // [E]
    unsigned* binned   = ssrc + E;          // [E]
    ushort*   feats    = (ushort*)(binned + E);  // [N][192] bf16

    int nChunksM = (M + SCAN_CHUNK - 1) / SCAN_CHUNK;

    k_bin_hist<<<NBLK, 256, 0, stream>>>(dstv, bcntT, E, EPB, NB);
    k_chunk_scan<<<nChunksM, 256, 0, stream>>>(bcntT, bbaseT, partials, M);
    k_scan_partials<<<1, 64, 0, stream>>>(partials, nChunksM);
    k_add_base<<<(M + 255) / 256, 256, 0, stream>>>(bbaseT, partials, M);
    k_bin_scatter<<<NBLK, 256, 0, stream>>>(srcv, dstv, bbaseT, binned, E, EPB, NB);
    k_bucket_csr<<<NB, 256, 0, stream>>>(binned, bbaseT, offs, cnt, ssrc, E, NB, N);

    k_gather<<<(N + 3) / 4, 256, 0, stream>>>(x, ssrc, offs, cnt, feats, N);
    k_mlp_mfma<<<1024, 256, 0, stream>>>(feats, W, b, out, N);
}